// Round 2
// baseline (815.363 us; speedup 1.0000x reference)
//
#include <hip/hip_runtime.h>
#include <hip/hip_bf16.h>

// y[n][o] = sum_r sum_m A[r][n][m] * Z[r][m][o],  Z_r = X @ W_r^T
// R=8, N=4096, F=128, fp32 in/out. HBM floor: A = 512 MiB read once ~85us.
//
// Pipeline:
//  1) zt_kernel:  Zt[r][o][m] = bf16(X @ W_r^T)^T  (8 MB at d_ws+0)
//  2) rgcn_main:  partial[r][ks] = bf16(A_r chunk) @ Zt_r^T  via MFMA,
//     grid (32 mtiles x 8 r -> blockIdx.x, 4 ksplit), NO LDS / NO barriers /
//     NO atomics; 1-deep A prefetch; coalesced f32x4 partial stores (64 MB
//     at d_ws+8MB). r in low 3 bits of blockIdx.x -> XCD i caches Zt[r=i].
//  3) reduce_kernel: out[n][o] = sum of 32 partials (coalesced reads,
//     scattered 4B writes into the 2MB output, L2-absorbed).

#define NN 4096
#define FF 128
#define RR 8
#define KSPLIT 4
#define CHUNK (NN / KSPLIT)   // 1024
#define ITERS (CHUNK / 32)    // 32
#define NPART (RR * KSPLIT)   // 32 partials per output element
#define PELEMS (NN * FF)      // 524288 floats per partial

typedef __attribute__((ext_vector_type(4))) float  f32x4;
typedef __attribute__((ext_vector_type(8))) __bf16 bf16x8;
typedef __attribute__((ext_vector_type(4))) __bf16 bf16x4;
typedef __attribute__((ext_vector_type(4))) short  s16x4;

union Frag { unsigned u[4]; bf16x8 v; };

// RNE fp32->bf16 via hardware (v_cvt_pk_bf16_f32 on gfx950)
__device__ __forceinline__ bf16x8 cvt8(f32x4 x0, f32x4 x1) {
  return __builtin_convertvector(
      __builtin_shufflevector(x0, x1, 0, 1, 2, 3, 4, 5, 6, 7), bf16x8);
}

// manual RNE (kept for zt_kernel, verbatim from passing R1 kernel)
__device__ __forceinline__ unsigned pk2bf(float a, float b) {
  unsigned ua = __builtin_bit_cast(unsigned, a);
  unsigned ub = __builtin_bit_cast(unsigned, b);
  ua = (ua + (((ua >> 16) & 1u) + 0x7fffu)) >> 16;
  ub = (ub + (((ub >> 16) & 1u) + 0x7fffu)) >> 16;
  return ua | (ub << 16);
}
__device__ __forceinline__ unsigned short f2bf(float a) {
  unsigned ua = __builtin_bit_cast(unsigned, a);
  return (unsigned short)((ua + (((ua >> 16) & 1u) + 0x7fffu)) >> 16);
}
__device__ __forceinline__ void cvt_frag(Frag& f, const f32x4& x0, const f32x4& x1) {
  f.u[0] = pk2bf(x0.x, x0.y);
  f.u[1] = pk2bf(x0.z, x0.w);
  f.u[2] = pk2bf(x1.x, x1.y);
  f.u[3] = pk2bf(x1.z, x1.w);
}

// Kernel 1: Zt[r][o][m] = sum_f X[m][f] * W[r][o][f]  (bf16, m contiguous)
__global__ __launch_bounds__(256, 2)
void zt_kernel(const float* __restrict__ X, const float* __restrict__ W,
               unsigned short* __restrict__ Zt) {
  const int lane = threadIdx.x & 63;
  const int wave = threadIdx.x >> 6;
  const int quad = lane >> 4;
  const int l16  = lane & 15;
  const int m0   = blockIdx.x * 128 + wave * 32;
  const int r    = blockIdx.y;
  const float* Wr = W + (size_t)r * FF * FF;

  f32x4 acc[2][8] = {};

  #pragma unroll
  for (int k = 0; k < FF; k += 32) {
    Frag a[2], b[8];
    #pragma unroll
    for (int mt = 0; mt < 2; ++mt) {
      const float* p = X + (size_t)(m0 + mt * 16 + l16) * FF + k + quad * 8;
      cvt_frag(a[mt], *(const f32x4*)p, *(const f32x4*)(p + 4));
    }
    #pragma unroll
    for (int nt = 0; nt < 8; ++nt) {
      const float* p = Wr + (size_t)(nt * 16 + l16) * FF + k + quad * 8;
      cvt_frag(b[nt], *(const f32x4*)p, *(const f32x4*)(p + 4));
    }
    #pragma unroll
    for (int mt = 0; mt < 2; ++mt)
      #pragma unroll
      for (int nt = 0; nt < 8; ++nt)
        acc[mt][nt] = __builtin_amdgcn_mfma_f32_16x16x32_bf16(
            a[mt].v, b[nt].v, acc[mt][nt], 0, 0, 0);
  }

  unsigned short* Zr = Zt + (size_t)r * FF * NN;
  #pragma unroll
  for (int mt = 0; mt < 2; ++mt)
    #pragma unroll
    for (int nt = 0; nt < 8; ++nt) {
      const int o = nt * 16 + l16;
      const int m = m0 + mt * 16 + quad * 4;
      s16x4 v;
      v.x = (short)f2bf(acc[mt][nt].x);
      v.y = (short)f2bf(acc[mt][nt].y);
      v.z = (short)f2bf(acc[mt][nt].z);
      v.w = (short)f2bf(acc[mt][nt].w);
      *(s16x4*)(Zr + (size_t)o * NN + m) = v;
    }
}

// Kernel 2: P[r*KSPLIT+ks] += A_r[mtile rows][k chunk] @ Zt_r^T
// grid (256 = 32 mtiles x 8 r, KSPLIT). Wave owns 32 rows x 128 cols.
__global__ __launch_bounds__(256, 3)
void rgcn_main(const float* __restrict__ A, const unsigned short* __restrict__ Zt,
               float* __restrict__ P) {
  const int lane  = threadIdx.x & 63;
  const int wave  = threadIdx.x >> 6;
  const int quad  = lane >> 4;
  const int l16   = lane & 15;
  const int r     = blockIdx.x & 7;   // low bits -> XCD round-robin keys on r
  const int mtile = blockIdx.x >> 3;
  const int ks    = blockIdx.y;
  const int m0    = mtile * 128 + wave * 32;
  const int k0    = ks * CHUNK;

  const float* Ar = A + (size_t)r * NN * NN;
  const unsigned short* Zr = Zt + (size_t)r * FF * NN;

  const float* pa0 = Ar + (size_t)(m0 + l16) * NN + quad * 8 + k0;
  const float* pa1 = pa0 + (size_t)16 * NN;
  const unsigned short* pb = Zr + (size_t)l16 * NN + quad * 8 + k0;

  f32x4 acc[2][8] = {};

  // software pipeline: A (HBM) prefetched one iteration ahead
  f32x4 nx0 = *(const f32x4*)(pa0);
  f32x4 nx1 = *(const f32x4*)(pa0 + 4);
  f32x4 ny0 = *(const f32x4*)(pa1);
  f32x4 ny1 = *(const f32x4*)(pa1 + 4);

  #pragma unroll 2
  for (int it = 0; it < ITERS; ++it) {
    const int k = it * 32;
    bf16x8 b[8];
    #pragma unroll
    for (int nt = 0; nt < 8; ++nt)
      b[nt] = *(const bf16x8*)(pb + (size_t)nt * 16 * NN + k);

    f32x4 cx0 = nx0, cx1 = nx1, cy0 = ny0, cy1 = ny1;
    if (it + 1 < ITERS) {
      nx0 = *(const f32x4*)(pa0 + k + 32);
      nx1 = *(const f32x4*)(pa0 + k + 36);
      ny0 = *(const f32x4*)(pa1 + k + 32);
      ny1 = *(const f32x4*)(pa1 + k + 36);
    }

    bf16x8 a0 = cvt8(cx0, cx1);
    bf16x8 a1 = cvt8(cy0, cy1);

    #pragma unroll
    for (int nt = 0; nt < 8; ++nt)
      acc[0][nt] = __builtin_amdgcn_mfma_f32_16x16x32_bf16(a0, b[nt], acc[0][nt], 0, 0, 0);
    #pragma unroll
    for (int nt = 0; nt < 8; ++nt)
      acc[1][nt] = __builtin_amdgcn_mfma_f32_16x16x32_bf16(a1, b[nt], acc[1][nt], 0, 0, 0);
  }

  // Coalesced partial store in register-native order:
  // float index = ((p*128 + gbw)*16 + inst)*256 + lane*4 + reg
  const int p   = r * KSPLIT + ks;
  const int gbw = mtile * 4 + wave;
  float* Pp = P + ((size_t)(p * 128 + gbw) * 16) * 256;
  #pragma unroll
  for (int mt = 0; mt < 2; ++mt)
    #pragma unroll
    for (int nt = 0; nt < 8; ++nt)
      *(f32x4*)(Pp + (mt * 8 + nt) * 256 + lane * 4) = acc[mt][nt];
}

// Kernel 3: out = sum of 32 partials; decode register-native flat index.
__global__ __launch_bounds__(256)
void reduce_kernel(const float* __restrict__ P, float* __restrict__ out) {
  const int t = blockIdx.x * 256 + threadIdx.x;
  float s = 0.f;
  #pragma unroll
  for (int p = 0; p < NPART; ++p) s += P[(size_t)p * PELEMS + t];
  const int reg  = t & 3;
  const int lane = (t >> 2) & 63;
  const int inst = (t >> 8) & 15;
  const int gbw  = t >> 12;
  const int quad = lane >> 4, l16 = lane & 15;
  const int mt   = inst >> 3, nt = inst & 7;
  const int row  = gbw * 32 + mt * 16 + quad * 4 + reg;
  const int col  = nt * 16 + l16;
  out[(size_t)row * FF + col] = s;
}

extern "C" void kernel_launch(void* const* d_in, const int* in_sizes, int n_in,
                              void* d_out, int out_size, void* d_ws, size_t ws_size,
                              hipStream_t stream) {
  const float* A = (const float*)d_in[0];  // [8][4096][4096]
  const float* X = (const float*)d_in[1];  // [4096][128]
  const float* W = (const float*)d_in[2];  // [8][128][128]
  float* out = (float*)d_out;              // [4096][128]

  unsigned short* Zt = (unsigned short*)d_ws;                    // 8 MB bf16
  float* P = (float*)((char*)d_ws + (size_t)RR * FF * NN * 2);   // 64 MB fp32

  zt_kernel<<<dim3(NN / 128, RR), 256, 0, stream>>>(X, W, Zt);
  rgcn_main<<<dim3(32 * RR, KSPLIT), 256, 0, stream>>>(A, Zt, P);
  reduce_kernel<<<dim3(PELEMS / 256), 256, 0, stream>>>(P, out);
}